// Round 2
// baseline (116.350 us; speedup 1.0000x reference)
//
#include <hip/hip_runtime.h>
#include <math.h>

typedef __attribute__((ext_vector_type(8))) short bf16x8;   // 8 bf16 (4 VGPRs)
typedef __attribute__((ext_vector_type(4))) float f32x4;    // MFMA acc

#define SQRT3F     1.7320508075688772f
#define SCALE_T    0.17677669529663687f    // 1/sqrt(32)
#define SCALE_M1   0.025515518153991442f   // C_SCALAR/sqrt(32)
#define SCALE_M2   0.014731391274719739f   // C_SCALAR*inv_sqrt3/sqrt(32)
#define SCALE_M34  0.036084391824351615f   // C_SCALAR/4

#define FSTR 40    // feature row stride (shorts): 80 B
#define ASTR 72    // agg row stride (shorts): 144 B (16B-aligned, bank-spread)

__device__ __forceinline__ ushort f2bf(float f) {
    union { float f; unsigned u; } v; v.f = f;
    unsigned u = v.u;
    return (ushort)((u + 0x7FFFu + ((u >> 16) & 1u)) >> 16);
}
__device__ __forceinline__ float bf2f(ushort h) {
    union { unsigned u; float f; } v; v.u = ((unsigned)h) << 16;
    return v.f;
}
__device__ __forceinline__ f32x4 mfma(bf16x8 a, bf16x8 b, f32x4 c) {
    return __builtin_amdgcn_mfma_f32_16x16x32_bf16(a, b, c, 0, 0, 0);
}
// stage-1 D-tile -> agg[n][u0..u0+3] (4 consecutive u), bf16 packed
__device__ __forceinline__ void storeAgg(ushort* AG, f32x4 t, int u0, int n) {
    uint2 u;
    u.x = f2bf(t[0]) | ((unsigned)f2bf(t[1]) << 16);
    u.y = f2bf(t[2]) | ((unsigned)f2bf(t[3]) << 16);
    *(uint2*)&AG[n*ASTR + u0] = u;
}
// residual + relu RMW of 4 consecutive nodes at channel c (packed uint2)
__device__ __forceinline__ void rmw4(ushort* F, int c, int n0, f32x4 h) {
    uint2* p = (uint2*)&F[c*FSTR + n0];
    uint2 o = *p;
    float f0 = bf2f((ushort)(o.x      )) + fmaxf(h[0], 0.f);
    float f1 = bf2f((ushort)(o.x >> 16)) + fmaxf(h[1], 0.f);
    float f2 = bf2f((ushort)(o.y      )) + fmaxf(h[2], 0.f);
    float f3 = bf2f((ushort)(o.y >> 16)) + fmaxf(h[3], 0.f);
    uint2 w;
    w.x = f2bf(f0) | ((unsigned)f2bf(f1) << 16);
    w.y = f2bf(f2) | ((unsigned)f2bf(f3) << 16);
    *p = w;
}

// ---------------------------------------------------------------------------
// Prep (tiny, one-shot): Tbf = bf16(emb@W_s2n * sT)  (100x32)
//   Mbf[lyr][row][64]: rows 0..31 = MsT[w][u], rows 32..47 = MvT[w][u],
//   cols 48..63 zero (K-pad). Executed ONCE.
// ---------------------------------------------------------------------------
__global__ void prep_kernel(const float* __restrict__ emb,
                            const float* __restrict__ W_s2n,
                            const float* __restrict__ W1, const float* __restrict__ W2,
                            const float* __restrict__ W3, const float* __restrict__ W4,
                            const float* __restrict__ Ws, const float* __restrict__ Wv,
                            ushort* __restrict__ Tbf, ushort* __restrict__ Mbf)
{
    int idx = blockIdx.x * blockDim.x + threadIdx.x;
    if (idx < 3200) {
        int r = idx >> 5, c = idx & 31;
        float acc = 0.f;
        for (int k = 0; k < 32; ++k) acc += emb[r*32 + k] * W_s2n[k*32 + c];
        Tbf[idx] = f2bf(acc * SCALE_T);
        return;
    }
    idx -= 3200;
    if (idx < 3*48*64) {
        int lyr = idx / 3072, rem = idx % 3072;
        int row = rem >> 6, u = rem & 63;
        float val = 0.f;
        if (row < 32) {
            int w = row;
            if (u < 32) {
                float a = 0.f;
                for (int k = 0; k < 32; ++k)
                    a += W1[lyr*1024 + u*32 + k] * Ws[lyr*1024 + k*32 + w];
                val = a * SCALE_M1;
            } else if (u < 48) {
                int uu = u - 32; float a = 0.f;
                for (int k = 0; k < 32; ++k)
                    a += W4[lyr*512 + uu*32 + k] * Ws[lyr*1024 + k*32 + w];
                val = a * SCALE_M2;
            }
        } else {
            int w = row - 32;
            if (u < 32) {
                float a = 0.f;
                for (int k = 0; k < 16; ++k)
                    a += W2[lyr*512 + u*16 + k] * Wv[lyr*256 + k*16 + w];
                val = a * SCALE_M34;
            } else if (u < 48) {
                int uu = u - 32; float a = 0.f;
                for (int k = 0; k < 16; ++k)
                    a += W3[lyr*256 + uu*16 + k] * Wv[lyr*256 + k*16 + w];
                val = a * SCALE_M34;
            }
        }
        Mbf[lyr*3072 + row*64 + u] = f2bf(val);
    }
}

// ---------------------------------------------------------------------------
// Fused GNN + MLP: TWO waves per graph (split by node-tile r = wave&1).
// 4 graphs/block, 512 threads, 512 blocks -> 16 waves/CU (was 8).
// Per-wave critical path halves: each wave owns node tile r (stage-1 agg
// rows r*16.., stage-2 output nodes r*16..). AG halves are disjoint (no
// sync needed); F needs 2 block barriers per layer (frag loads read all
// 32 nodes, RMW writes own half). LDS unchanged: 44.2 KB -> 2 blocks/CU.
// ---------------------------------------------------------------------------
__global__ __launch_bounds__(512, 4)
void gnn_kernel(const float* __restrict__ pos, const int* __restrict__ z,
                const ushort* __restrict__ Tbf, const ushort* __restrict__ Mbf,
                const float* __restrict__ Wr1, const float* __restrict__ br1,
                const float* __restrict__ Wr2, const float* __restrict__ br2,
                float* __restrict__ out, int B)
{
    __shared__ __align__(16) char smem[45312];
    ushort* featA = (ushort*)smem;                    // 4*80*40*2 = 25600 B
    ushort* aggA  = (ushort*)(smem + 25600);          // 4*32*72*2 = 18432 B (per GRAPH now)
    float*  hgl   = (float*)(smem + 44032);           // 4*80*4    = 1280 B
    float*  h1    = (float*)aggA;                     // alias (post-layers)

    const int tid = threadIdx.x;
    const int wv = tid >> 6, l = tid & 63;
    const int wg = wv >> 1, r = wv & 1;               // graph-in-block, node-tile role
    const int g  = blockIdx.x*4 + wg;
    ushort* F  = featA + wg*80*FSTR;
    ushort* AG = aggA  + wg*32*ASTR;

    // zero K-pad cols 48..63 of own AG rows (only cols stage-2 reads)
    {
        #pragma unroll
        for (int t2 = 0; t2 < 2; ++t2) {
            int i = t2*64 + l;                        // 0..127
            int row = r*16 + (i >> 3);
            ((uint*)AG)[row*36 + 24 + (i & 7)] = 0;
        }
    }
    // zero v feature rows (48 rows x 20 uints = 960 uints; half per wave)
    for (int i = l; i < 480; i += 64)
        ((uint*)(F + 32*FSTR))[r*480 + i] = 0;

    // s init: own 16 nodes. 64 lanes = 16 nodes x 4 channel-quarters.
    {
        int n = r*16 + (l & 15), h = l >> 4;
        int zg = z[g*32 + n];
        uint4 t0 = *(const uint4*)(Tbf + zg*32 + h*8);
        unsigned ua[4] = {t0.x, t0.y, t0.z, t0.w};
        #pragma unroll
        for (int q = 0; q < 4; ++q) {
            F[(h*8 + 2*q    )*FSTR + n] = (ushort)ua[q];
            F[(h*8 + 2*q + 1)*FSTR + n] = (ushort)(ua[q] >> 16);
        }
    }

    // adjacency fragments for OWN node-columns only (nt = r): 16 VGPRs
    const int ln = l & 15, kq = l >> 4;
    bf16x8 adjf[4];
    {
        const int k0 = kq*8;
        int ng = g*32 + r*16 + ln;
        float px = pos[3*ng], py = pos[3*ng+1], pz = pos[3*ng+2];
        union { bf16x8 v; ushort s[8]; } o[4];
        #pragma unroll
        for (int jj = 0; jj < 8; ++jj) {
            int j = g*32 + k0 + jj;
            float dx = __fsub_rn(px, pos[3*j]);
            float dy = __fsub_rn(py, pos[3*j+1]);
            float dz = __fsub_rn(pz, pos[3*j+2]);
            float d2 = __fadd_rn(__fadd_rn(__fmul_rn(dx,dx), __fmul_rn(dy,dy)),
                                 __fmul_rn(dz,dz));
            bool on = (d2 <= 25.0f) && (d2 > 0.0f);
            float rinv = on ? rsqrtf(d2) * SQRT3F : 0.f;
            o[0].s[jj] = on ? (ushort)0x3F80 : (ushort)0;   // bf16(1.0)
            o[1].s[jj] = f2bf(dx * rinv);
            o[2].s[jj] = f2bf(dy * rinv);
            o[3].s[jj] = f2bf(dz * rinv);
        }
        #pragma unroll
        for (int w = 0; w < 4; ++w) adjf[w] = o[w].v;
    }

    const f32x4 z4 = {0.f, 0.f, 0.f, 0.f};
    __syncthreads();                                  // init (F, AG-pad) complete

    for (int lay = 0; lay < 3; ++lay) {
        const ushort* Mg = Mbf + lay*3072;
        // feature fragments (pre-update values, ALL 32 nodes)
        bf16x8 fs0 = *(const bf16x8*)&F[(     ln)*FSTR + kq*8];
        bf16x8 fs1 = *(const bf16x8*)&F[(16 + ln)*FSTR + kq*8];
        bf16x8 fv0 = *(const bf16x8*)&F[(32 + ln)*FSTR + kq*8];
        bf16x8 fv1 = *(const bf16x8*)&F[(48 + ln)*FSTR + kq*8];
        bf16x8 fv2 = *(const bf16x8*)&F[(64 + ln)*FSTR + kq*8];
        // M fragments for this layer (global, L1-hot)
        bf16x8 bmS0[2], bmS1[2], bmV[2];
        #pragma unroll
        for (int kc = 0; kc < 2; ++kc) {
            bmS0[kc] = *(const bf16x8*)&Mg[(     ln)*64 + kc*32 + kq*8];
            bmS1[kc] = *(const bf16x8*)&Mg[(16 + ln)*64 + kc*32 + kq*8];
            bmV [kc] = *(const bf16x8*)&Mg[(32 + ln)*64 + kc*32 + kq*8];
        }
        __syncthreads();   // all frag loads done -> F half-writes may begin

        // ---- scalar path (own node tile only)
        {
            f32x4 t;
            t = mfma(fs0, adjf[0], z4);
            storeAgg(AG, t,      kq*4, r*16 + ln);
            t = mfma(fs1, adjf[0], z4);
            storeAgg(AG, t, 16 + kq*4, r*16 + ln);
            t = mfma(fv2, adjf[3], z4);
            t = mfma(fv1, adjf[2], t);
            t = mfma(fv0, adjf[1], t);
            storeAgg(AG, t, 32 + kq*4, r*16 + ln);
        }
        f32x4 hs[2] = {z4, z4};                       // [w-tile]
        #pragma unroll
        for (int kc = 0; kc < 2; ++kc) {
            bf16x8 ag = *(const bf16x8*)&AG[(r*16 + ln)*ASTR + kc*32 + kq*8];
            hs[0] = mfma(ag, bmS0[kc], hs[0]);
            hs[1] = mfma(ag, bmS1[kc], hs[1]);
        }
        rmw4(F,      ln, r*16 + kq*4, hs[0]);
        rmw4(F, 16 + ln, r*16 + kq*4, hs[1]);

        // ---- vector path, one spatial component i at a time (reuses AG rows)
        #pragma unroll
        for (int i = 0; i < 3; ++i) {
            bf16x8 fvi = (i == 0) ? fv0 : (i == 1) ? fv1 : fv2;
            {
                f32x4 t;
                t = mfma(fs0, adjf[1+i], z4);
                storeAgg(AG, t,      kq*4, r*16 + ln);
                t = mfma(fs1, adjf[1+i], z4);
                storeAgg(AG, t, 16 + kq*4, r*16 + ln);
                t = mfma(fvi, adjf[0], z4);
                storeAgg(AG, t, 32 + kq*4, r*16 + ln);
            }
            f32x4 hv = z4;
            #pragma unroll
            for (int kc = 0; kc < 2; ++kc) {
                bf16x8 ag = *(const bf16x8*)&AG[(r*16 + ln)*ASTR + kc*32 + kq*8];
                hv = mfma(ag, bmV[kc], hv);
            }
            rmw4(F, 32 + i*16 + ln, r*16 + kq*4, hv);
        }
        __syncthreads();   // both waves' F updates visible
    }

    // wave-local sum-pool: wave r handles channels [r*40, r*40+40)
    if (l < 40) {
        int f = r*40 + l;
        const ushort* row;
        if (f < 32) row = &F[f*FSTR];
        else { int c = f - 32, w = c/3, i = c - 3*w; row = &F[(32 + i*16 + w)*FSTR]; }
        const uint* r32 = (const uint*)row;
        float acc = 0.f;
        #pragma unroll
        for (int q = 0; q < 16; ++q) {
            uint u = r32[q];
            acc += bf2f((ushort)u) + bf2f((ushort)(u >> 16));
        }
        hgl[wg*80 + f] = acc;
    }
    __syncthreads();   // hgl complete; aggA free for h1 alias

    // --- fused MLP head (block = its 4 graphs, 512 threads) ---
    {
        const int w = tid & 255, gh = tid >> 8;       // gh: graph pair {0,1} / {2,3}
        float a0 = br1[w], a1 = a0;
        const float* hg0 = &hgl[(gh*2    )*80];
        const float* hg1 = &hgl[(gh*2 + 1)*80];
        #pragma unroll 4
        for (int f = 0; f < 80; ++f) {
            float wvv = Wr1[f*256 + w];
            a0 = fmaf(hg0[f], wvv, a0);
            a1 = fmaf(hg1[f], wvv, a1);
        }
        h1[(gh*2    )*256 + w] = fmaxf(a0, 0.f);
        h1[(gh*2 + 1)*256 + w] = fmaxf(a1, 0.f);
    }
    __syncthreads();
    {
        const int w2 = tid & 127, gi = tid >> 7;      // one (graph, out-col) per thread
        const float4* h1v = (const float4*)&h1[gi*256];
        float s = 0.f;
        #pragma unroll 2
        for (int k4 = 0; k4 < 64; ++k4) {
            float4 hh = h1v[k4];
            int k = k4 * 4;
            float m0 = Wr2[(size_t)(k+0)*128 + w2];
            float m1 = Wr2[(size_t)(k+1)*128 + w2];
            float m2 = Wr2[(size_t)(k+2)*128 + w2];
            float m3 = Wr2[(size_t)(k+3)*128 + w2];
            s = fmaf(hh.x,m0, fmaf(hh.y,m1, fmaf(hh.z,m2, fmaf(hh.w,m3, s))));
        }
        out[(size_t)(blockIdx.x*4 + gi)*128 + w2] = s + br2[w2];
    }
}

// ---------------------------------------------------------------------------
extern "C" void kernel_launch(void* const* d_in, const int* in_sizes, int n_in,
                              void* d_out, int out_size, void* d_ws, size_t ws_size,
                              hipStream_t stream)
{
    const float* pos   = (const float*)d_in[0];
    const int*   z     = (const int*)d_in[1];
    const float* emb   = (const float*)d_in[5];
    const float* W_s2n = (const float*)d_in[6];
    const float* W1    = (const float*)d_in[7];
    const float* W2    = (const float*)d_in[8];
    const float* W3    = (const float*)d_in[9];
    const float* W4    = (const float*)d_in[10];
    const float* Ws    = (const float*)d_in[11];
    const float* Wv    = (const float*)d_in[12];
    const float* Wr1   = (const float*)d_in[13];
    const float* br1   = (const float*)d_in[14];
    const float* Wr2   = (const float*)d_in[15];
    const float* br2   = (const float*)d_in[16];
    float* out = (float*)d_out;

    const int B = out_size / 128;      // graphs (2048)

    // workspace: Tbf (3200 shorts) | Mbf (9216 shorts)
    char* p = (char*)d_ws;
    ushort* Tbf = (ushort*)p;  p += 6400;
    ushort* Mbf = (ushort*)p;  p += 18432;

    const int prep_total = 3200 + 3*48*64;
    prep_kernel<<<(prep_total + 255) / 256, 256, 0, stream>>>(
        emb, W_s2n, W1, W2, W3, W4, Ws, Wv, Tbf, Mbf);

    gnn_kernel<<<B / 4, 512, 0, stream>>>(pos, z, Tbf, Mbf,
                                          Wr1, br1, Wr2, br2, out, B);
}